// Round 2
// baseline (42.431 us; speedup 1.0000x reference)
//
#include <hip/hip_runtime.h>
#include <math.h>

// Reference applies T = (I + i*flip)/sqrt(2) = exp(i*(pi/4)*flip), `size` times.
// T^n = cos(n*pi/4)*I + i*sin(n*pi/4)*flip.
// Harness output = REAL PART only (complex64 coerced to float32):
//   out[b][j] = c*xr[b][j] - s*xi[b][dim-1-j],  c=cos(n*pi/4), s=sin(n*pi/4).
// size=22: n%8==6 -> c=0, s=-1  =>  out[b][j] = xi[b][dim-1-j]  (pure flip).

__global__ void FixedXMixing_kernel(const float* __restrict__ xr,
                                    const float* __restrict__ xi,
                                    const int* __restrict__ size_ptr,
                                    float* __restrict__ out,
                                    long long n_total) {
    const int size = *size_ptr;                 // broadcast scalar load
    const long long dim  = 1ll << size;
    const long long mask = dim - 1;

    // c, s for n = size (mod 8); wave-uniform.
    const int m = size & 7;
    const float INV_SQRT2 = 0.70710678118654752f;
    const float ctab[8] = {1.f, INV_SQRT2, 0.f, -INV_SQRT2, -1.f, -INV_SQRT2, 0.f, INV_SQRT2};
    const float stab[8] = {0.f, INV_SQRT2, 1.f, INV_SQRT2, 0.f, -INV_SQRT2, -1.f, -INV_SQRT2};
    const float c = ctab[m];
    const float s = stab[m];

    long long tid    = (long long)blockIdx.x * blockDim.x + threadIdx.x;
    long long stride = (long long)gridDim.x * blockDim.x;
    const long long nquads = n_total >> 2;      // 4 floats per thread

    if (c == 0.0f) {
        // out[j] = -s * xi[dim-1-j] : pure (negated) row reversal, xr unread.
        for (long long q = tid; q < nquads; q += stride) {
            const long long i0 = q << 2;
            const long long b  = i0 >> size;
            const long long j  = i0 & mask;
            const long long src = b * dim + (dim - 4 - j);   // 16B-aligned
            const float4 vi = *reinterpret_cast<const float4*>(xi + src);
            // out[i0+k] = -s * xi[dim-1-j-k] -> k=0 uses .w ... k=3 uses .x
            const float4 o = make_float4(-s * vi.w, -s * vi.z, -s * vi.y, -s * vi.x);
            *reinterpret_cast<float4*>(out + i0) = o;
        }
    } else {
        for (long long q = tid; q < nquads; q += stride) {
            const long long i0 = q << 2;
            const long long b  = i0 >> size;
            const long long j  = i0 & mask;
            const long long src = b * dim + (dim - 4 - j);
            const float4 vr = *reinterpret_cast<const float4*>(xr + i0);  // forward
            const float4 vi = *reinterpret_cast<const float4*>(xi + src); // reversed
            const float4 o = make_float4(c * vr.x - s * vi.w,
                                         c * vr.y - s * vi.z,
                                         c * vr.z - s * vi.y,
                                         c * vr.w - s * vi.x);
            *reinterpret_cast<float4*>(out + i0) = o;
        }
    }
}

extern "C" void kernel_launch(void* const* d_in, const int* in_sizes, int n_in,
                              void* d_out, int out_size, void* d_ws, size_t ws_size,
                              hipStream_t stream) {
    const float* xr = (const float*)d_in[0];
    const float* xi = (const float*)d_in[1];
    const int* size_ptr = (const int*)d_in[2];
    float* out = (float*)d_out;

    const long long n_total = (long long)out_size;   // float32 elements (= BATCH*dim)
    const long long nquads = n_total >> 2;

    const int block = 256;
    long long want = (nquads + block - 1) / block;
    int grid = (int)((want < 65535) ? want : 65535);
    if (grid < 1) grid = 1;

    FixedXMixing_kernel<<<grid, block, 0, stream>>>(xr, xi, size_ptr, out, n_total);
}